// Round 6
// baseline (241.279 us; speedup 1.0000x reference)
//
#include <hip/hip_runtime.h>
#include <math.h>

constexpr int Dn = 4096;     // C*H*W (row length)
constexpr int Bn = 4096;     // batch
constexpr int NCLS = 10;
constexpr int CH = 8;        // rows per chunk == waves per pass12 block
constexpr int NBLK0 = Bn / 256;         // 16 pass0 blocks
constexpr int MAXCH = Bn / CH + NCLS;   // 522 grid upper bound

// Workspace layout (float/int units). NO pre-zeroing needed:
// every slot is written exactly once by plain stores before being read
// (lbuf accumulation is LDS-local).
constexpr int OFF_CEB  = 0;      // 16 floats: per-block CE sums
constexpr int OFF_CNT  = 16;     // 16*10 ints: blkcnt[b][c]
constexpr int OFF_XS   = 176;    // 1 float (zeroed by pass0 block 0)
constexpr int OFF_DONE = 177;    // 1 int   (zeroed by pass0 block 0)
constexpr int OFF_ORDB = 192;    // 16*10*256 ints: ORDB[b][c][r]
constexpr int OFF_P    = 41216;  // partials: MAXCH * 4096 floats (16B aligned)

// ---------------------------------------------------------------- pass 0
// CE + argmax + block-local class lists. 16 blocks x 256. NO global atomics.
__global__ __launch_bounds__(256) void pass0_ce_order(
    const float* __restrict__ outputs, const int* __restrict__ y,
    float* __restrict__ ws)
{
    const int t = threadIdx.x;
    const int b = blockIdx.x;
    const int i = b * 256 + t;
    const int w = t >> 6, lane = t & 63;
    int* wsi = (int*)ws;

    __shared__ int hist[NCLS];
    __shared__ float sce[4];
    if (t < NCLS) hist[t] = 0;
    __syncthreads();

    const float* o = outputs + (size_t)i * NCLS;
    float m = o[0]; int am = 0;
    #pragma unroll
    for (int k = 1; k < NCLS; ++k) { float ok = o[k]; if (ok > m) { m = ok; am = k; } }
    float se = 0.f;
    #pragma unroll
    for (int k = 0; k < NCLS; ++k) se += expf(o[k] - m);
    float ce = m + logf(se) - o[y[i]];

    int rank = atomicAdd(&hist[am], 1);              // LDS atomic only
    wsi[OFF_ORDB + (b * NCLS + am) * 256 + rank] = i;

    #pragma unroll
    for (int off = 32; off; off >>= 1) ce += __shfl_down(ce, off, 64);
    if (lane == 0) sce[w] = ce;
    __syncthreads();

    if (t < NCLS) wsi[OFF_CNT + b * NCLS + t] = hist[t];
    if (t == 0) ws[OFF_CEB + b] = sce[0] + sce[1] + sce[2] + sce[3];
    if (b == 0 && t == 32) { ws[OFF_XS] = 0.f; wsi[OFF_DONE] = 0; }
}

// ---------------------------------------------------------------- pass 12
// Rounds 0-5 ledger: the compiler NEVER keeps float4 v[16] live (VGPR_Count
// 40-44 in every shape); it silently re-reads the row from global for each
// of the min / ss / scale passes, and performance tracks TLP available to
// hide that reload latency (R0: 16 waves/CU fast; R5: 8 waves/CU slow).
// Fix: make the live set small ALGEBRAICALLY. Moment identity
//   ss = sum(g-mn)^2 = sum(g^2) + mn*(D*mn - 2*sum(g))
// -> pass 1 streams the row once accumulating (min, sum, sumsq) in 3
// scalars; pass 2 re-reads (L2-hit, just touched) and ds_add_f32's into the
// swizzled 16 KB accumulator (proven exact R1/R2/R5). Live set ~30 VGPR =
// spill-immune at any block size, so: 512 threads / 8 waves / 1 row per
// wave / CH=8 / grid 522 ~ 16.3 waves/CU (full TLP) + 8.6 MB partials.
__global__ __launch_bounds__(512) void pass12_fused(
    const float* __restrict__ grad, float* __restrict__ ws)
{
    const int* wsi = (const int*)ws;
    const int t = threadIdx.x, w = t >> 6, lane = t & 63;

    __shared__ int lcnt[NBLK0 * NCLS];   // blkcnt[b][c]
    __shared__ int tot[NCLS];
    __shared__ float lbuf[Dn];           // 16 KB chunk accumulator

    #pragma unroll
    for (int i = 0; i < 2; ++i)
        ((float4*)lbuf)[t + 512 * i] = make_float4(0.f, 0.f, 0.f, 0.f);
    if (t < NBLK0 * NCLS) lcnt[t] = wsi[OFF_CNT + t];
    __syncthreads();
    if (t < NCLS) {
        int s = 0;
        #pragma unroll
        for (int bb = 0; bb < NBLK0; ++bb) s += lcnt[bb * NCLS + t];
        tot[t] = s;
    }
    __syncthreads();

    // chunk map: blockIdx.x -> (class c, global start s0, class count cnt)
    int c = -1, s0 = 0, cnt = 0;
    {
        int bidx = (int)blockIdx.x, acc = 0;
        #pragma unroll
        for (int k = 0; k < NCLS; ++k) {
            int n = tot[k];
            int nch = (n + CH - 1) / CH;
            if (c < 0 && bidx < acc + nch) { c = k; s0 = (bidx - acc) * CH; cnt = n; }
            acc += nch;
        }
    }
    if (c < 0) return;                   // uniform per block, after all barriers
    const int m = min(CH, cnt - s0);
    const int s = (lane >> 3) & 3;       // bank-spread XOR swizzle

    if (w < m) {
        // map class-rank r -> source pass0 block + local pos
        int idx;
        {
            const int r = s0 + w;
            int pref = 0, src = 0, loc = 0;
            #pragma unroll
            for (int bb = 0; bb < NBLK0; ++bb) {
                int n = lcnt[bb * NCLS + c];
                if (r >= pref && r < pref + n) { src = bb; loc = r - pref; }
                pref += n;
            }
            idx = wsi[OFF_ORDB + (src * NCLS + c) * 256 + loc];
        }
        const float4* row = (const float4*)grad + (size_t)idx * (Dn / 4);

        // ---- pass 1: stream row, fold (min, sum, sumsq); nothing kept live
        float mn = 3.4e38f, sg = 0.f, sg2 = 0.f;
        #pragma unroll
        for (int k = 0; k < 16; ++k) {
            float4 v = row[k * 64 + lane];
            mn = fminf(mn, fminf(fminf(v.x, v.y), fminf(v.z, v.w)));
            sg += (v.x + v.y) + (v.z + v.w);
            sg2 = fmaf(v.x, v.x, fmaf(v.y, v.y, fmaf(v.z, v.z, fmaf(v.w, v.w, sg2))));
        }
        #pragma unroll
        for (int off = 1; off < 64; off <<= 1) {
            mn  = fminf(mn, __shfl_xor(mn, off, 64));
            sg  += __shfl_xor(sg, off, 64);
            sg2 += __shfl_xor(sg2, off, 64);
        }

        // ss = sum(g-mn)^2 via moment identity (no cancellation: terms all
        // ~same sign and magnitude >> eps for this data)
        const float ss = fmaf(mn, fmaf((float)Dn, mn, -2.f * sg), sg2);
        const float a = 1.0f / sqrtf(ss);    // min-max range cancels under L2
        const float b = -mn * a;

        // ---- pass 2: re-read row (L2-hit) and accumulate into lbuf.
        // element e = k*256 + 4*lane + comp lives at lbuf[bk + (s^comp)]
        // (bijective within each aligned quad; 2 lanes/bank = free, m136).
        #pragma unroll
        for (int k = 0; k < 16; ++k) {
            float4 v = row[k * 64 + lane];
            const int bk = k * 256 + 4 * lane;
            atomicAdd(&lbuf[bk + (s ^ 0)], fmaf(v.x, a, b));
            atomicAdd(&lbuf[bk + (s ^ 1)], fmaf(v.y, a, b));
            atomicAdd(&lbuf[bk + (s ^ 2)], fmaf(v.z, a, b));
            atomicAdd(&lbuf[bk + (s ^ 3)], fmaf(v.w, a, b));
        }
    }
    __syncthreads();

    // un-swizzle (writer of float4-quad q is lane q&63 -> s=(q>>3)&3, same
    // involution) and store the chunk partial row, fully coalesced.
    float4* Pc = (float4*)(ws + OFF_P) + (size_t)blockIdx.x * (Dn / 4);
    #pragma unroll
    for (int i = 0; i < 2; ++i) {
        const int q = t + 512 * i;
        float4 u = ((const float4*)lbuf)[q];
        const int st = (q >> 3) & 3;
        float a0 = u.x, a1 = u.y, a2 = u.z, a3 = u.w;
        if (st & 1) { float tm = a0; a0 = a1; a1 = tm; tm = a2; a2 = a3; a3 = tm; }
        if (st & 2) { float tm = a0; a0 = a2; a2 = tm; tm = a1; a1 = a3; a3 = tm; }
        Pc[q] = make_float4(a0, a1, a2, a3);
    }
}

// ---------------------------------------------------------------- pass 34
// Reduce chunk partials per class (~52 chunks/class, 8.6 MB total, freshly
// written -> L2/L3-warm), square, sum; last block finalizes. 64-thread
// blocks, grid 640: spreads the latency-bound chunk loop over all CUs with
// ~52 independent loads/thread of ILP.
__global__ __launch_bounds__(64) void pass34_final(
    float* __restrict__ ws, float* __restrict__ out)
{
    const int t = threadIdx.x;
    const int idx = blockIdx.x * 64 + t;     // 0 .. 40959
    const int c = idx >> 12;                 // class (uniform per block)
    const int j = idx & (Dn - 1);
    const int* wsi = (const int*)ws;

    __shared__ int tot[NCLS];
    if (t < NCLS) {
        int s = 0;
        #pragma unroll
        for (int bb = 0; bb < NBLK0; ++bb) s += wsi[OFF_CNT + bb * NCLS + t];
        tot[t] = s;
    }
    __syncthreads();

    int cs = 0, ce2 = 0;
    {
        int acc = 0;
        #pragma unroll
        for (int k = 0; k < NCLS; ++k) {
            int nch = (tot[k] + CH - 1) / CH;
            if (k == c) { cs = acc; ce2 = acc + nch; }
            acc += nch;
        }
    }

    const float* P = ws + OFF_P;
    float s = 0.f;
    int ch = cs;
    for (; ch + 4 <= ce2; ch += 4)
        s += P[(size_t)(ch + 0) * Dn + j] + P[(size_t)(ch + 1) * Dn + j]
           + P[(size_t)(ch + 2) * Dn + j] + P[(size_t)(ch + 3) * Dn + j];
    for (; ch < ce2; ++ch) s += P[(size_t)ch * Dn + j];
    float p = s * s;

    #pragma unroll
    for (int off = 32; off; off >>= 1) p += __shfl_down(p, off, 64);
    if (t == 0) {
        atomicAdd(&ws[OFF_XS], p);
        __threadfence();
        int ticket = atomicAdd(&((int*)ws)[OFF_DONE], 1);
        if (ticket == (NCLS * Dn / 64) - 1) {
            float xs = atomicAdd(&ws[OFF_XS], 0.0f);   // coherent read
            double n2 = 0.0;
            #pragma unroll
            for (int k = 0; k < NCLS; ++k) { double nc = (double)tot[k]; n2 += nc * nc; }
            double cesum = 0.0;
            #pragma unroll
            for (int k = 0; k < NBLK0; ++k) cesum += (double)ws[OFF_CEB + k];
            double xloss = (n2 - (double)xs) / (2.0 * (double)Bn);
            out[0] = (float)(cesum / (double)Bn + xloss);
        }
    }
}

extern "C" void kernel_launch(void* const* d_in, const int* in_sizes, int n_in,
                              void* d_out, int out_size, void* d_ws, size_t ws_size,
                              hipStream_t stream)
{
    const float* outputs = (const float*)d_in[0];   // [4096,10] f32
    const float* grad    = (const float*)d_in[1];   // [4096,1,64,64] f32
    const int*   y       = (const int*)d_in[2];     // [4096] i32
    float* ws  = (float*)d_ws;
    float* out = (float*)d_out;

    pass0_ce_order<<<NBLK0, 256, 0, stream>>>(outputs, y, ws);
    pass12_fused<<<MAXCH, 512, 0, stream>>>(grad, ws);
    pass34_final<<<NCLS * Dn / 64, 64, 0, stream>>>(ws, out);
}

// Round 7
// 124.568 us; speedup vs baseline: 1.9369x; 1.9369x over previous
//
#include <hip/hip_runtime.h>
#include <math.h>

constexpr int Dn = 4096;     // C*H*W (row length)
constexpr int Bn = 4096;     // batch
constexpr int NCLS = 10;
constexpr int CH = 8;        // rows per chunk == waves per pass12 block
constexpr int NBLK0 = Bn / 256;         // 16 pass0 blocks
constexpr int MAXCH = Bn / CH + NCLS;   // 522 grid upper bound

// Workspace layout (float/int units). NO pre-zeroing needed:
// every slot is written exactly once by plain stores before being read.
constexpr int OFF_CEB  = 0;      // 16 floats: per-block CE sums
constexpr int OFF_CNT  = 16;     // 16*10 ints: blkcnt[b][c]
constexpr int OFF_XS   = 176;    // 1 float (zeroed by pass0 block 0)
constexpr int OFF_DONE = 177;    // 1 int   (zeroed by pass0 block 0)
constexpr int OFF_ORDB = 192;    // 16*10*256 ints: ORDB[b][c][r]
constexpr int OFF_P    = 41216;  // partials: MAXCH * 4096 floats (16B aligned)

// ---------------------------------------------------------------- pass 0
// CE + argmax + block-local class lists. 16 blocks x 256. NO global atomics.
__global__ __launch_bounds__(256) void pass0_ce_order(
    const float* __restrict__ outputs, const int* __restrict__ y,
    float* __restrict__ ws)
{
    const int t = threadIdx.x;
    const int b = blockIdx.x;
    const int i = b * 256 + t;
    const int w = t >> 6, lane = t & 63;
    int* wsi = (int*)ws;

    __shared__ int hist[NCLS];
    __shared__ float sce[4];
    if (t < NCLS) hist[t] = 0;
    __syncthreads();

    const float* o = outputs + (size_t)i * NCLS;
    float m = o[0]; int am = 0;
    #pragma unroll
    for (int k = 1; k < NCLS; ++k) { float ok = o[k]; if (ok > m) { m = ok; am = k; } }
    float se = 0.f;
    #pragma unroll
    for (int k = 0; k < NCLS; ++k) se += expf(o[k] - m);
    float ce = m + logf(se) - o[y[i]];

    int rank = atomicAdd(&hist[am], 1);              // LDS atomic only (tiny)
    wsi[OFF_ORDB + (b * NCLS + am) * 256 + rank] = i;

    #pragma unroll
    for (int off = 32; off; off >>= 1) ce += __shfl_down(ce, off, 64);
    if (lane == 0) sce[w] = ce;
    __syncthreads();

    if (t < NCLS) wsi[OFF_CNT + b * NCLS + t] = hist[t];
    if (t == 0) ws[OFF_CEB + b] = sce[0] + sce[1] + sce[2] + sce[3];
    if (b == 0 && t == 32) { ws[OFF_XS] = 0.f; wsi[OFF_DONE] = 0; }
}

// ---------------------------------------------------------------- pass 12
// Rounds 0-6 ledger, distilled:
//  - bulk LDS atomics are a ~100us structure at this volume (R1/R2/R5/R6
//    all >=138us regardless of spill/TLP; every atomic-free version <43us)
//    -> combine must use PLAIN ds_write/ds_read.
//  - the compiler never keeps float4 v[16] live (VGPR 40-64 everywhere)
//    -> never hold a row in registers across phases.
//  - moment identity ss = sumsq + mn*(D*mn - 2*sum) is exact on this data
//    (R6 absmax 0.0) -> stats from ONE streaming pass, no re-read.
// Structure: 512 thr / 8 waves / CH=8 rows / 131KB LDS (1 block/CU, grid
// 522 ~ 2 rounds). Pass 1: each wave streams its row HBM->LDS (plain b128
// writes) folding (min,sum,sumsq) in 3 scalars; butterfly; lane0 publishes
// (a,b). ONE barrier. Combine: 512 threads read each row once from LDS
// (linear b128, conflict-free, ~128 instrs/block ~ 1.5us), FMA with
// per-row a, add Sum(b) once, write coalesced 8.6MB partials.
__global__ __launch_bounds__(512) void pass12_fused(
    const float* __restrict__ grad, float* __restrict__ ws)
{
    const int* wsi = (const int*)ws;
    const int t = threadIdx.x, w = t >> 6, lane = t & 63;

    __shared__ int lcnt[NBLK0 * NCLS];   // blkcnt[b][c]
    __shared__ int tot[NCLS];
    __shared__ float rows[CH][Dn];       // 128 KB row staging
    __shared__ float A8[CH], B8[CH];

    if (t < NBLK0 * NCLS) lcnt[t] = wsi[OFF_CNT + t];
    __syncthreads();
    if (t < NCLS) {
        int s = 0;
        #pragma unroll
        for (int bb = 0; bb < NBLK0; ++bb) s += lcnt[bb * NCLS + t];
        tot[t] = s;
    }
    __syncthreads();

    // chunk map: blockIdx.x -> (class c, global start s0, class count cnt)
    int c = -1, s0 = 0, cnt = 0;
    {
        int bidx = (int)blockIdx.x, acc = 0;
        #pragma unroll
        for (int k = 0; k < NCLS; ++k) {
            int n = tot[k];
            int nch = (n + CH - 1) / CH;
            if (c < 0 && bidx < acc + nch) { c = k; s0 = (bidx - acc) * CH; cnt = n; }
            acc += nch;
        }
    }
    if (c < 0) return;                   // block-uniform, after all barriers
    const int m = min(CH, cnt - s0);     // >=1 for any active block

    if (w < m) {
        // map class-rank r -> source pass0 block + local pos
        int idx;
        {
            const int r = s0 + w;
            int pref = 0, src = 0, loc = 0;
            #pragma unroll
            for (int bb = 0; bb < NBLK0; ++bb) {
                int n = lcnt[bb * NCLS + c];
                if (r >= pref && r < pref + n) { src = bb; loc = r - pref; }
                pref += n;
            }
            idx = wsi[OFF_ORDB + (src * NCLS + c) * 256 + loc];
        }
        const float4* row = (const float4*)grad + (size_t)idx * (Dn / 4);
        float4* rw = (float4*)rows[w];

        // single streaming pass: HBM -> LDS + (min, sum, sumsq) fold
        float mn = 3.4e38f, sg = 0.f, sg2 = 0.f;
        #pragma unroll
        for (int k = 0; k < 16; ++k) {
            float4 v = row[k * 64 + lane];
            rw[k * 64 + lane] = v;
            mn = fminf(mn, fminf(fminf(v.x, v.y), fminf(v.z, v.w)));
            sg += (v.x + v.y) + (v.z + v.w);
            sg2 = fmaf(v.x, v.x, fmaf(v.y, v.y, fmaf(v.z, v.z, fmaf(v.w, v.w, sg2))));
        }
        #pragma unroll
        for (int off = 1; off < 64; off <<= 1) {
            mn  = fminf(mn, __shfl_xor(mn, off, 64));
            sg  += __shfl_xor(sg, off, 64);
            sg2 += __shfl_xor(sg2, off, 64);
        }
        if (lane == 0) {
            // ss = sum(g-mn)^2 via moment identity (verified exact, R6)
            const float ss = fmaf(mn, fmaf((float)Dn, mn, -2.f * sg), sg2);
            const float a = 1.0f / sqrtf(ss);   // min-max range cancels under L2
            A8[w] = a; B8[w] = -mn * a;
        }
    }
    __syncthreads();

    // combine: each thread sums its 2 float4-quads across the m rows.
    // Unused rows (r>=m) are skipped -> stale LDS never read, a-weights
    // never applied. Sum(b_r) folds in once per element.
    float sb = 0.f;
    for (int r = 0; r < m; ++r) sb += B8[r];

    float4* Pc = (float4*)(ws + OFF_P) + (size_t)blockIdx.x * (Dn / 4);
    #pragma unroll
    for (int i = 0; i < 2; ++i) {
        const int q = t + 512 * i;
        float ox = sb, oy = sb, oz = sb, ow = sb;
        if (m == CH) {                       // common case: full unroll
            #pragma unroll
            for (int r = 0; r < CH; ++r) {
                float4 u = ((const float4*)rows[r])[q];
                const float a = A8[r];
                ox = fmaf(u.x, a, ox); oy = fmaf(u.y, a, oy);
                oz = fmaf(u.z, a, oz); ow = fmaf(u.w, a, ow);
            }
        } else {                             // tail chunk (<=1 per class)
            for (int r = 0; r < m; ++r) {
                float4 u = ((const float4*)rows[r])[q];
                const float a = A8[r];
                ox = fmaf(u.x, a, ox); oy = fmaf(u.y, a, oy);
                oz = fmaf(u.z, a, oz); ow = fmaf(u.w, a, ow);
            }
        }
        Pc[q] = make_float4(ox, oy, oz, ow);
    }
}

// ---------------------------------------------------------------- pass 34
// Reduce chunk partials per class (~52 chunks/class, 8.6 MB total, freshly
// written -> L2/L3-warm), square, sum; last block finalizes. 64-thread
// blocks, grid 640: spreads the latency-bound chunk loop over all CUs with
// ~52 independent loads/thread of ILP.
__global__ __launch_bounds__(64) void pass34_final(
    float* __restrict__ ws, float* __restrict__ out)
{
    const int t = threadIdx.x;
    const int idx = blockIdx.x * 64 + t;     // 0 .. 40959
    const int c = idx >> 12;                 // class (uniform per block)
    const int j = idx & (Dn - 1);
    const int* wsi = (const int*)ws;

    __shared__ int tot[NCLS];
    if (t < NCLS) {
        int s = 0;
        #pragma unroll
        for (int bb = 0; bb < NBLK0; ++bb) s += wsi[OFF_CNT + bb * NCLS + t];
        tot[t] = s;
    }
    __syncthreads();

    int cs = 0, ce2 = 0;
    {
        int acc = 0;
        #pragma unroll
        for (int k = 0; k < NCLS; ++k) {
            int nch = (tot[k] + CH - 1) / CH;
            if (k == c) { cs = acc; ce2 = acc + nch; }
            acc += nch;
        }
    }

    const float* P = ws + OFF_P;
    float s = 0.f;
    int ch = cs;
    for (; ch + 4 <= ce2; ch += 4)
        s += P[(size_t)(ch + 0) * Dn + j] + P[(size_t)(ch + 1) * Dn + j]
           + P[(size_t)(ch + 2) * Dn + j] + P[(size_t)(ch + 3) * Dn + j];
    for (; ch < ce2; ++ch) s += P[(size_t)ch * Dn + j];
    float p = s * s;

    #pragma unroll
    for (int off = 32; off; off >>= 1) p += __shfl_down(p, off, 64);
    if (t == 0) {
        atomicAdd(&ws[OFF_XS], p);
        __threadfence();
        int ticket = atomicAdd(&((int*)ws)[OFF_DONE], 1);
        if (ticket == (NCLS * Dn / 64) - 1) {
            float xs = atomicAdd(&ws[OFF_XS], 0.0f);   // coherent read
            double n2 = 0.0;
            #pragma unroll
            for (int k = 0; k < NCLS; ++k) { double nc = (double)tot[k]; n2 += nc * nc; }
            double cesum = 0.0;
            #pragma unroll
            for (int k = 0; k < NBLK0; ++k) cesum += (double)ws[OFF_CEB + k];
            double xloss = (n2 - (double)xs) / (2.0 * (double)Bn);
            out[0] = (float)(cesum / (double)Bn + xloss);
        }
    }
}

extern "C" void kernel_launch(void* const* d_in, const int* in_sizes, int n_in,
                              void* d_out, int out_size, void* d_ws, size_t ws_size,
                              hipStream_t stream)
{
    const float* outputs = (const float*)d_in[0];   // [4096,10] f32
    const float* grad    = (const float*)d_in[1];   // [4096,1,64,64] f32
    const int*   y       = (const int*)d_in[2];     // [4096] i32
    float* ws  = (float*)d_ws;
    float* out = (float*)d_out;

    pass0_ce_order<<<NBLK0, 256, 0, stream>>>(outputs, y, ws);
    pass12_fused<<<MAXCH, 512, 0, stream>>>(grad, ws);
    pass34_final<<<NCLS * Dn / 64, 64, 0, stream>>>(ws, out);
}